// Round 14
// baseline (468.740 us; speedup 1.0000x reference)
//
#include <hip/hip_runtime.h>
#include <hip/hip_bf16.h>

#define NN 50000
#define NE 800000

typedef __bf16 bf16_t;
typedef unsigned short u16;
typedef bf16_t bf16x4 __attribute__((ext_vector_type(4)));
typedef bf16_t bf16x8 __attribute__((ext_vector_type(8)));
typedef float f32x4 __attribute__((ext_vector_type(4)));

// 8-element MFMA A/B fragment: {p[0..3], p[16..19]} (two k-halves of 16x16x32).
__device__ __forceinline__ bf16x8 load_frag(const bf16_t* p) {
    bf16x4 lo = *(const bf16x4*)p;
    bf16x4 hi = *(const bf16x4*)(p + 16);
    bf16x8 f;
    f[0] = lo[0]; f[1] = lo[1]; f[2] = lo[2]; f[3] = lo[3];
    f[4] = hi[0]; f[5] = hi[1]; f[6] = hi[2]; f[7] = hi[3];
    return f;
}

// ---------------- fused weight prep (+ deg zeroing) ----------------
__global__ void k_prepall(const float* __restrict__ mw1, const float* __restrict__ uw1,
                          const float* __restrict__ uw2,
                          const float* __restrict__ mw2, const float* __restrict__ mb2,
                          const float* __restrict__ ow,
                          bf16_t* __restrict__ w1t, bf16_t* __restrict__ u1t,
                          bf16_t* __restrict__ u2t,
                          bf16_t* __restrict__ w2u, float* __restrict__ cvec,
                          bf16_t* __restrict__ whi, bf16_t* __restrict__ wlo,
                          int* __restrict__ deg) {
    int gid = blockIdx.x * blockDim.x + threadIdx.x;
    int nthr = gridDim.x * blockDim.x;
    for (int i = gid; i < NN; i += nthr) deg[i] = 0;
    if (gid < 3 * 64 * 128) {
        int l = gid / 8192, r = gid % 8192, hid = r >> 7, k = r & 127;
        w1t[gid] = (bf16_t)mw1[l * 8192 + k * 64 + hid];
    }
    if (gid < 3 * 64 * 64) {
        int l = gid / 4096, r = gid % 4096, hid = r >> 6, k = r & 63;
        u1t[gid] = (bf16_t)uw1[l * 8192 + k * 64 + hid];
        u2t[gid] = (bf16_t)uw2[l * 4096 + k * 64 + hid];
        float s = 0.f;
        for (int j = 0; j < 64; ++j)
            s += mw2[l * 4096 + k * 64 + j] * uw1[l * 8192 + (64 + j) * 64 + hid];
        w2u[l * 4096 + hid * 64 + k] = (bf16_t)s;
    }
    if (gid < 3 * 64) {
        int l = gid / 64, hid = gid % 64;
        float s = 0.f;
        for (int j = 0; j < 64; ++j)
            s += mb2[l * 64 + j] * uw1[l * 8192 + (64 + j) * 64 + hid];
        cvec[gid] = s;
    }
    if (gid < 128 * 64) {
        int j = gid >> 6, k = gid & 63;
        float w = ow[k * 128 + j];
        bf16_t hi = (bf16_t)w;
        whi[gid] = hi;
        wlo[gid] = (bf16_t)(w - (float)hi);
    }
}

// ---------------- counting sort of edges by destination ----------------
__global__ void k_hist(const int* __restrict__ ei, int* __restrict__ deg) {
    int gid = blockIdx.x * blockDim.x + threadIdx.x;
    if (gid < NE) atomicAdd(&deg[ei[NE + gid]], 1);
}

#define SCAN_BLKS 196
__global__ void k_scan1(const int* __restrict__ deg, int* __restrict__ tscan,
                        int* __restrict__ part) {
    __shared__ int lds[256];
    int tid = threadIdx.x;
    int gid = blockIdx.x * 256 + tid;
    int v = (gid < NN) ? deg[gid] : 0;
    lds[tid] = v;
    __syncthreads();
    for (int off = 1; off < 256; off <<= 1) {
        int t = (tid >= off) ? lds[tid - off] : 0;
        __syncthreads();
        lds[tid] += t;
        __syncthreads();
    }
    if (gid < NN) tscan[gid] = lds[tid] - v;
    if (tid == 255) part[blockIdx.x] = lds[255];
}

// fused scan2+scan3
__global__ void k_scan23(const int* __restrict__ tscan, const int* __restrict__ part,
                         int* __restrict__ offs, int* __restrict__ cursor) {
    __shared__ int lds[256];
    int tid = threadIdx.x;
    int v = (tid < SCAN_BLKS) ? part[tid] : 0;
    lds[tid] = v;
    __syncthreads();
    for (int off = 1; off < 256; off <<= 1) {
        int t = (tid >= off) ? lds[tid - off] : 0;
        __syncthreads();
        lds[tid] += t;
        __syncthreads();
    }
    __shared__ int base;
    if (tid == 0) base = (blockIdx.x > 0) ? lds[blockIdx.x - 1] : 0;
    __syncthreads();
    int gid = blockIdx.x * 256 + tid;
    if (gid < NN) {
        int o = tscan[gid] + base;
        offs[gid] = o;
        cursor[gid] = o;
    }
    if (gid == 0) offs[NN] = NE;
}

__global__ void k_scatter(const int* __restrict__ ei, int* __restrict__ cursor,
                          u16* __restrict__ ssrc) {
    int gid = blockIdx.x * blockDim.x + threadIdx.x;
    if (gid < NE) {
        int c = ei[NE + gid];
        int pos = atomicAdd(&cursor[c], 1);
        ssrc[pos] = (u16)ei[gid];
    }
}

// ---------------- fused input projection + layer-0 P/Q ----------------
__global__ __launch_bounds__(256)
void k_inputpq(const float* __restrict__ x, const float* __restrict__ iw,
               const float* __restrict__ ib,
               const bf16_t* __restrict__ w1t, const float* __restrict__ b1,
               bf16_t* __restrict__ h, bf16_t* __restrict__ P, bf16_t* __restrict__ Q) {
    const int lane = threadIdx.x & 63;
    const int g = lane >> 4;
    const int m16 = lane & 15;
    const int wid = (blockIdx.x * blockDim.x + threadIdx.x) >> 6;
    const int nw = (gridDim.x * blockDim.x) >> 6;

    bf16x8 wtop[2][4], wbot[2][4];
    #pragma unroll
    for (int s = 0; s < 2; ++s)
        #pragma unroll
        for (int nt = 0; nt < 4; ++nt) {
            wtop[s][nt] = load_frag(w1t + (16 * nt + m16) * 128 + 32 * s + 4 * g);
            wbot[s][nt] = load_frag(w1t + (16 * nt + m16) * 128 + 64 + 32 * s + 4 * g);
        }
    float b1f[4][4];
    #pragma unroll
    for (int nt = 0; nt < 4; ++nt)
        #pragma unroll
        for (int r = 0; r < 4; ++r) b1f[nt][r] = b1[16 * nt + 4 * g + r];

    float wcol[3][2][8], bcol[2][8];
    #pragma unroll
    for (int s = 0; s < 2; ++s)
        #pragma unroll
        for (int j = 0; j < 8; ++j) {
            int f = 32 * s + 4 * g + (j < 4 ? j : 16 + j - 4);
            bcol[s][j] = ib[f];
            #pragma unroll
            for (int i = 0; i < 3; ++i) wcol[i][s][j] = iw[i * 64 + f];
        }

    const int ntiles = NN / 16;
    for (int t = wid; t < ntiles; t += nw) {
        const int node = t * 16 + m16;
        float x0 = x[node * 3 + 0], x1 = x[node * 3 + 1], x2 = x[node * 3 + 2];
        bf16x8 hb[2];
        #pragma unroll
        for (int s = 0; s < 2; ++s)
            #pragma unroll
            for (int j = 0; j < 8; ++j) {
                float hf = bcol[s][j] + x0 * wcol[0][s][j] + x1 * wcol[1][s][j]
                         + x2 * wcol[2][s][j];
                hb[s][j] = (bf16_t)hf;
            }
        #pragma unroll
        for (int s = 0; s < 2; ++s) {
            bf16x4 lo, hi;
            #pragma unroll
            for (int j = 0; j < 4; ++j) { lo[j] = hb[s][j]; hi[j] = hb[s][4 + j]; }
            *(bf16x4*)(h + node * 64 + 32 * s + 4 * g) = lo;
            *(bf16x4*)(h + node * 64 + 32 * s + 16 + 4 * g) = hi;
        }

        f32x4 accP[4], accQ[4];
        #pragma unroll
        for (int nt = 0; nt < 4; ++nt) {
            accP[nt] = (f32x4){0.f, 0.f, 0.f, 0.f};
            accQ[nt] = (f32x4){0.f, 0.f, 0.f, 0.f};
        }
        #pragma unroll
        for (int s = 0; s < 2; ++s)
            #pragma unroll
            for (int nt = 0; nt < 4; ++nt) {
                accP[nt] = __builtin_amdgcn_mfma_f32_16x16x32_bf16(wtop[s][nt], hb[s], accP[nt], 0, 0, 0);
                accQ[nt] = __builtin_amdgcn_mfma_f32_16x16x32_bf16(wbot[s][nt], hb[s], accQ[nt], 0, 0, 0);
            }
        #pragma unroll
        for (int nt = 0; nt < 4; ++nt) {
            bf16x4 vp, vq;
            #pragma unroll
            for (int r = 0; r < 4; ++r) {
                vp[r] = (bf16_t)accP[nt][r];
                vq[r] = (bf16_t)(accQ[nt][r] + b1f[nt][r]);
            }
            *(bf16x4*)(P + node * 64 + 16 * nt + 4 * g) = vp;
            *(bf16x4*)(Q + node * 64 + 16 * nt + 4 * g) = vq;
        }
    }
}

// ---------------- merged per-layer kernel: edge gather (LDS S) + update + next P/Q ----------------
// Block = 64 nodes. Phase 1: thread=(node, feature-quarter) gathers its node's
// edges (16 streams/wave), f32-accumulates, stores Sl[64][67] (odd stride, ~2-way
// banks). One barrier. Phase 2: 4 waves run the update MLP (+ next-layer P/Q),
// S-fragments built from LDS. Kills the S/S2 global round-trip + 2 launches/layer.
__global__ __launch_bounds__(256)
void k_layer(const bf16_t* __restrict__ h, const bf16_t* __restrict__ P,
             const bf16_t* __restrict__ Q,
             const u16* __restrict__ ssrc, const int* __restrict__ offs,
             const int* __restrict__ deg,
             const bf16_t* __restrict__ u1t, const bf16_t* __restrict__ w2u,
             const bf16_t* __restrict__ u2t,
             const float* __restrict__ ub1, const float* __restrict__ cvec,
             const float* __restrict__ ub2,
             const bf16_t* __restrict__ w1tn, const float* __restrict__ b1n,
             const int do_pq,
             bf16_t* __restrict__ hn, bf16_t* __restrict__ Pn, bf16_t* __restrict__ Qn) {
    __shared__ float Sl[64][67];
    const int tid = threadIdx.x;

    // ---- phase 1: edge gather ----
    {
        const int nl = tid >> 2;          // node local 0..63
        const int f2 = tid & 3;           // feature quarter (16 feats)
        const int node = blockIdx.x * 64 + nl;
        float qf[16], a[16];
        #pragma unroll
        for (int r = 0; r < 16; ++r) a[r] = 0.f;
        if (node < NN) {
            bf16x8 q0 = *(const bf16x8*)(Q + node * 64 + f2 * 16);
            bf16x8 q1 = *(const bf16x8*)(Q + node * 64 + f2 * 16 + 8);
            #pragma unroll
            for (int r = 0; r < 8; ++r) { qf[r] = (float)q0[r]; qf[8 + r] = (float)q1[r]; }
            const int beg = offs[node], end = offs[node + 1];
            int p = beg;
            const int n2 = beg + ((end - beg) & ~1);
            for (; p < n2; p += 2) {
                int s0 = ssrc[p], s1 = ssrc[p + 1];
                const bf16_t* p0 = P + s0 * 64 + f2 * 16;
                const bf16_t* p1 = P + s1 * 64 + f2 * 16;
                bf16x8 v00 = *(const bf16x8*)p0;
                bf16x8 v01 = *(const bf16x8*)(p0 + 8);
                bf16x8 v10 = *(const bf16x8*)p1;
                bf16x8 v11 = *(const bf16x8*)(p1 + 8);
                #pragma unroll
                for (int r = 0; r < 8; ++r) {
                    float x0 = (float)v00[r] + qf[r];
                    float x1 = (float)v10[r] + qf[r];
                    float y0 = (float)v01[r] + qf[8 + r];
                    float y1 = (float)v11[r] + qf[8 + r];
                    a[r]     += (x0 > 0.f ? x0 : 0.f) + (x1 > 0.f ? x1 : 0.f);
                    a[8 + r] += (y0 > 0.f ? y0 : 0.f) + (y1 > 0.f ? y1 : 0.f);
                }
            }
            for (; p < end; ++p) {
                int s = ssrc[p];
                const bf16_t* pp = P + s * 64 + f2 * 16;
                bf16x8 v0 = *(const bf16x8*)pp;
                bf16x8 v1 = *(const bf16x8*)(pp + 8);
                #pragma unroll
                for (int r = 0; r < 8; ++r) {
                    float x = (float)v0[r] + qf[r];
                    float y = (float)v1[r] + qf[8 + r];
                    a[r]     += x > 0.f ? x : 0.f;
                    a[8 + r] += y > 0.f ? y : 0.f;
                }
            }
        }
        #pragma unroll
        for (int r = 0; r < 16; ++r) Sl[nl][f2 * 16 + r] = a[r];
    }
    __syncthreads();

    // ---- phase 2: update MLP + next-layer P/Q ----
    const int lane = tid & 63;
    const int w = tid >> 6;
    const int g = lane >> 4;
    const int m16 = lane & 15;
    const int nl2 = w * 16 + m16;
    const int node = blockIdx.x * 64 + nl2;

    bf16x8 u1f[2][4], w2f[2][4], u2f[2][4], wtop[2][4], wbot[2][4];
    #pragma unroll
    for (int s = 0; s < 2; ++s)
        #pragma unroll
        for (int nt = 0; nt < 4; ++nt) {
            u1f[s][nt] = load_frag(u1t + (16 * nt + m16) * 64 + 32 * s + 4 * g);
            w2f[s][nt] = load_frag(w2u + (16 * nt + m16) * 64 + 32 * s + 4 * g);
            u2f[s][nt] = load_frag(u2t + (16 * nt + m16) * 64 + 32 * s + 4 * g);
        }
    if (do_pq) {
        #pragma unroll
        for (int s = 0; s < 2; ++s)
            #pragma unroll
            for (int nt = 0; nt < 4; ++nt) {
                wtop[s][nt] = load_frag(w1tn + (16 * nt + m16) * 128 + 32 * s + 4 * g);
                wbot[s][nt] = load_frag(w1tn + (16 * nt + m16) * 128 + 64 + 32 * s + 4 * g);
            }
    }
    float b1f[4][4], cf[4][4], b2f[4][4], b1nf[4][4];
    #pragma unroll
    for (int nt = 0; nt < 4; ++nt)
        #pragma unroll
        for (int r = 0; r < 4; ++r) {
            b1f[nt][r] = ub1[16 * nt + 4 * g + r];
            cf[nt][r] = cvec[16 * nt + 4 * g + r];
            b2f[nt][r] = ub2[16 * nt + 4 * g + r];
            b1nf[nt][r] = do_pq ? b1n[16 * nt + 4 * g + r] : 0.f;
        }

    bf16x8 hfr[2], sfr[2];
    hfr[0] = load_frag(h + node * 64 + 4 * g);
    hfr[1] = load_frag(h + node * 64 + 4 * g + 32);
    #pragma unroll
    for (int s = 0; s < 2; ++s) {
        bf16x8 f;
        #pragma unroll
        for (int j = 0; j < 4; ++j) {
            f[j]     = (bf16_t)Sl[nl2][32 * s + 4 * g + j];
            f[4 + j] = (bf16_t)Sl[nl2][32 * s + 16 + 4 * g + j];
        }
        sfr[s] = f;
    }
    float dv = (float)deg[node < NN ? node : 0];

    f32x4 acc1[4];
    #pragma unroll
    for (int nt = 0; nt < 4; ++nt) acc1[nt] = (f32x4){0.f, 0.f, 0.f, 0.f};
    #pragma unroll
    for (int s = 0; s < 2; ++s)
        #pragma unroll
        for (int nt = 0; nt < 4; ++nt) {
            acc1[nt] = __builtin_amdgcn_mfma_f32_16x16x32_bf16(u1f[s][nt], hfr[s], acc1[nt], 0, 0, 0);
            acc1[nt] = __builtin_amdgcn_mfma_f32_16x16x32_bf16(w2f[s][nt], sfr[s], acc1[nt], 0, 0, 0);
        }

    bf16x8 hb[2];
    #pragma unroll
    for (int s = 0; s < 2; ++s) {
        bf16x8 f;
        #pragma unroll
        for (int half = 0; half < 2; ++half) {
            const int nt = 2 * s + half;
            #pragma unroll
            for (int r = 0; r < 4; ++r) {
                float v = acc1[nt][r] + b1f[nt][r] + dv * cf[nt][r];
                v = v > 0.f ? v : 0.f;
                f[4 * half + r] = (bf16_t)v;
            }
        }
        hb[s] = f;
    }

    f32x4 acc2[4];
    #pragma unroll
    for (int nt = 0; nt < 4; ++nt) acc2[nt] = (f32x4){0.f, 0.f, 0.f, 0.f};
    #pragma unroll
    for (int s = 0; s < 2; ++s)
        #pragma unroll
        for (int nt = 0; nt < 4; ++nt)
            acc2[nt] = __builtin_amdgcn_mfma_f32_16x16x32_bf16(u2f[s][nt], hb[s], acc2[nt], 0, 0, 0);

    bf16x8 hb2[2];
    #pragma unroll
    for (int s = 0; s < 2; ++s) {
        bf16x8 f;
        #pragma unroll
        for (int half = 0; half < 2; ++half) {
            const int nt = 2 * s + half;
            #pragma unroll
            for (int r = 0; r < 4; ++r) {
                float v = acc2[nt][r] + b2f[nt][r];
                f[4 * half + r] = (bf16_t)(v > 0.f ? v : 0.f);
            }
        }
        hb2[s] = f;
    }
    if (node < NN) {
        #pragma unroll
        for (int s = 0; s < 2; ++s) {
            bf16x4 lo, hi;
            #pragma unroll
            for (int j = 0; j < 4; ++j) { lo[j] = hb2[s][j]; hi[j] = hb2[s][4 + j]; }
            *(bf16x4*)(hn + node * 64 + 32 * s + 4 * g) = lo;
            *(bf16x4*)(hn + node * 64 + 32 * s + 16 + 4 * g) = hi;
        }
    }

    if (do_pq) {
        f32x4 accP[4], accQ[4];
        #pragma unroll
        for (int nt = 0; nt < 4; ++nt) {
            accP[nt] = (f32x4){0.f, 0.f, 0.f, 0.f};
            accQ[nt] = (f32x4){0.f, 0.f, 0.f, 0.f};
        }
        #pragma unroll
        for (int s = 0; s < 2; ++s)
            #pragma unroll
            for (int nt = 0; nt < 4; ++nt) {
                accP[nt] = __builtin_amdgcn_mfma_f32_16x16x32_bf16(wtop[s][nt], hb2[s], accP[nt], 0, 0, 0);
                accQ[nt] = __builtin_amdgcn_mfma_f32_16x16x32_bf16(wbot[s][nt], hb2[s], accQ[nt], 0, 0, 0);
            }
        if (node < NN) {
            #pragma unroll
            for (int nt = 0; nt < 4; ++nt) {
                bf16x4 vp, vq;
                #pragma unroll
                for (int r = 0; r < 4; ++r) {
                    vp[r] = (bf16_t)accP[nt][r];
                    vq[r] = (bf16_t)(accQ[nt][r] + b1nf[nt][r]);
                }
                *(bf16x4*)(Pn + node * 64 + 16 * nt + 4 * g) = vp;
                *(bf16x4*)(Qn + node * 64 + 16 * nt + 4 * g) = vq;
            }
        }
    }
}

// ---------------- output projection (MFMA, split hi/lo weights) ----------------
__global__ __launch_bounds__(256)
void k_outm(const bf16_t* __restrict__ whi_t, const bf16_t* __restrict__ wlo_t,
            const bf16_t* __restrict__ h, const float* __restrict__ b,
            float* __restrict__ out) {
    const int lane = threadIdx.x & 63;
    const int g = lane >> 4;
    const int m16 = lane & 15;
    const int wid = (blockIdx.x * blockDim.x + threadIdx.x) >> 6;
    const int nw = (gridDim.x * blockDim.x) >> 6;

    bf16x8 whi[2][8], wlo[2][8];
    #pragma unroll
    for (int s = 0; s < 2; ++s)
        #pragma unroll
        for (int nt = 0; nt < 8; ++nt) {
            whi[s][nt] = load_frag(whi_t + (16 * nt + m16) * 64 + 32 * s + 4 * g);
            wlo[s][nt] = load_frag(wlo_t + (16 * nt + m16) * 64 + 32 * s + 4 * g);
        }
    f32x4 bfv[8];
    #pragma unroll
    for (int nt = 0; nt < 8; ++nt)
        #pragma unroll
        for (int r = 0; r < 4; ++r) bfv[nt][r] = b[16 * nt + 4 * g + r];

    const int ntiles = NN / 16;
    for (int t = wid; t < ntiles; t += nw) {
        const int node = t * 16 + m16;
        bf16x8 hfr[2];
        hfr[0] = load_frag(h + node * 64 + 4 * g);
        hfr[1] = load_frag(h + node * 64 + 4 * g + 32);

        f32x4 acc[8];
        #pragma unroll
        for (int nt = 0; nt < 8; ++nt) acc[nt] = (f32x4){0.f, 0.f, 0.f, 0.f};
        #pragma unroll
        for (int s = 0; s < 2; ++s)
            #pragma unroll
            for (int nt = 0; nt < 8; ++nt) {
                acc[nt] = __builtin_amdgcn_mfma_f32_16x16x32_bf16(whi[s][nt], hfr[s], acc[nt], 0, 0, 0);
                acc[nt] = __builtin_amdgcn_mfma_f32_16x16x32_bf16(wlo[s][nt], hfr[s], acc[nt], 0, 0, 0);
            }
        #pragma unroll
        for (int nt = 0; nt < 8; ++nt)
            *(f32x4*)(out + node * 128 + 16 * nt + 4 * g) = acc[nt] + bfv[nt];
    }
}

extern "C" void kernel_launch(void* const* d_in, const int* in_sizes, int n_in,
                              void* d_out, int out_size, void* d_ws, size_t ws_size,
                              hipStream_t stream) {
    const float* x      = (const float*)d_in[0];
    const int*   ei     = (const int*)d_in[1];
    const float* in_w   = (const float*)d_in[2];
    const float* in_b   = (const float*)d_in[3];
    const float* msg_w1 = (const float*)d_in[4];
    const float* msg_b1 = (const float*)d_in[5];
    const float* msg_w2 = (const float*)d_in[6];
    const float* msg_b2 = (const float*)d_in[7];
    const float* upd_w1 = (const float*)d_in[8];
    const float* upd_b1 = (const float*)d_in[9];
    const float* upd_w2 = (const float*)d_in[10];
    const float* upd_b2 = (const float*)d_in[11];
    const float* out_w  = (const float*)d_in[12];
    const float* out_b  = (const float*)d_in[13];
    float* out = (float*)d_out;

    char* ws = (char*)d_ws;
    bf16_t* h_a    = (bf16_t*)(ws);
    bf16_t* h_b    = (bf16_t*)(ws + 6400000);
    bf16_t* Pa     = (bf16_t*)(ws + 12800000);
    bf16_t* Qa     = (bf16_t*)(ws + 19200000);
    bf16_t* Pb     = (bf16_t*)(ws + 25600000);
    u16*    ssrc   = (u16*)   (ws + 32000000);   // 1.6 MB
    int*    deg    = (int*)   (ws + 35200000);
    int*    offs   = (int*)   (ws + 35400000);
    int*    cursor = (int*)   (ws + 35600128);
    int*    tscan  = (int*)   (ws + 35800192);
    int*    part   = (int*)   (ws + 36000256);
    bf16_t* w1t    = (bf16_t*)(ws + 36002304);
    bf16_t* u1t    = (bf16_t*)(ws + 36051456);
    bf16_t* u2t    = (bf16_t*)(ws + 36076032);
    bf16_t* w2u    = (bf16_t*)(ws + 36100608);
    float*  cvec   = (float*) (ws + 36125184);
    bf16_t* whi    = (bf16_t*)(ws + 36126208);   // 16 KB
    bf16_t* wlo    = (bf16_t*)(ws + 36142592);   // 16 KB
    bf16_t* Qb     = (bf16_t*)(ws + 36160000);   // 6.4 MB

    // fused weight prep + deg zeroing
    k_prepall<<<96, 256, 0, stream>>>(msg_w1, upd_w1, upd_w2, msg_w2, msg_b2, out_w,
                                      w1t, u1t, u2t, w2u, cvec, whi, wlo, deg);

    // counting sort of edges by destination
    k_hist<<<(NE + 255) / 256, 256, 0, stream>>>(ei, deg);
    k_scan1<<<SCAN_BLKS, 256, 0, stream>>>(deg, tscan, part);
    k_scan23<<<SCAN_BLKS, 256, 0, stream>>>(tscan, part, offs, cursor);
    k_scatter<<<(NE + 255) / 256, 256, 0, stream>>>(ei, cursor, ssrc);

    // fused input projection + layer-0 P/Q
    k_inputpq<<<512, 256, 0, stream>>>(x, in_w, in_b, w1t, msg_b1, h_a, Pa, Qa);

    const int NB = (NN + 63) / 64;   // 782
    bf16_t* hc = h_a; bf16_t* hn = h_b;
    bf16_t* Pc = Pa;  bf16_t* Qc = Qa;
    bf16_t* Pn = Pb;  bf16_t* Qn = Qb;
    for (int l = 0; l < 3; ++l) {
        int do_pq = (l < 2) ? 1 : 0;
        const bf16_t* w1tn = do_pq ? (w1t + (l + 1) * 8192) : w1t;
        const float*  b1n  = do_pq ? (msg_b1 + (l + 1) * 64) : msg_b1;
        k_layer<<<NB, 256, 0, stream>>>(hc, Pc, Qc, ssrc, offs, deg,
                                        u1t + l * 4096, w2u + l * 4096, u2t + l * 4096,
                                        upd_b1 + l * 64, cvec + l * 64, upd_b2 + l * 64,
                                        w1tn, b1n, do_pq, hn, Pn, Qn);
        bf16_t* t;
        t = hc; hc = hn; hn = t;
        t = Pc; Pc = Pn; Pn = t;
        t = Qc; Qc = Qn; Qn = t;
    }
    k_outm<<<640, 256, 0, stream>>>(whi, wlo, hc, out_b, out);
}

// Round 15
// 377.188 us; speedup vs baseline: 1.2427x; 1.2427x over previous
//
#include <hip/hip_runtime.h>
#include <hip/hip_bf16.h>

#define NN 50000
#define NE 800000

typedef __bf16 bf16_t;
typedef unsigned short u16;
typedef bf16_t bf16x4 __attribute__((ext_vector_type(4)));
typedef bf16_t bf16x8 __attribute__((ext_vector_type(8)));
typedef float f32x4 __attribute__((ext_vector_type(4)));

// 8-element MFMA A/B fragment: {p[0..3], p[16..19]} (two k-halves of 16x16x32).
__device__ __forceinline__ bf16x8 load_frag(const bf16_t* p) {
    bf16x4 lo = *(const bf16x4*)p;
    bf16x4 hi = *(const bf16x4*)(p + 16);
    bf16x8 f;
    f[0] = lo[0]; f[1] = lo[1]; f[2] = lo[2]; f[3] = lo[3];
    f[4] = hi[0]; f[5] = hi[1]; f[6] = hi[2]; f[7] = hi[3];
    return f;
}

// fragment = bf16(f32(a) + f32(b)) element-wise, for split-S reconstruction
__device__ __forceinline__ bf16x8 load_frag2(const bf16_t* p, const bf16_t* q) {
    bf16x8 a = load_frag(p);
    bf16x8 b = load_frag(q);
    bf16x8 f;
    #pragma unroll
    for (int j = 0; j < 8; ++j) f[j] = (bf16_t)((float)a[j] + (float)b[j]);
    return f;
}

// ---------------- fused weight prep (+ deg zeroing, replacing memset) ----------------
__global__ void k_prepall(const float* __restrict__ mw1, const float* __restrict__ uw1,
                          const float* __restrict__ uw2,
                          const float* __restrict__ mw2, const float* __restrict__ mb2,
                          const float* __restrict__ ow,
                          bf16_t* __restrict__ w1t, bf16_t* __restrict__ u1t,
                          bf16_t* __restrict__ u2t,
                          bf16_t* __restrict__ w2u, float* __restrict__ cvec,
                          bf16_t* __restrict__ whi, bf16_t* __restrict__ wlo,
                          int* __restrict__ deg) {
    int gid = blockIdx.x * blockDim.x + threadIdx.x;
    int nthr = gridDim.x * blockDim.x;
    for (int i = gid; i < NN; i += nthr) deg[i] = 0;
    if (gid < 3 * 64 * 128) {
        int l = gid / 8192, r = gid % 8192, hid = r >> 7, k = r & 127;
        w1t[gid] = (bf16_t)mw1[l * 8192 + k * 64 + hid];
    }
    if (gid < 3 * 64 * 64) {
        int l = gid / 4096, r = gid % 4096, hid = r >> 6, k = r & 63;
        u1t[gid] = (bf16_t)uw1[l * 8192 + k * 64 + hid];
        u2t[gid] = (bf16_t)uw2[l * 4096 + k * 64 + hid];
        float s = 0.f;
        for (int j = 0; j < 64; ++j)
            s += mw2[l * 4096 + k * 64 + j] * uw1[l * 8192 + (64 + j) * 64 + hid];
        w2u[l * 4096 + hid * 64 + k] = (bf16_t)s;
    }
    if (gid < 3 * 64) {
        int l = gid / 64, hid = gid % 64;
        float s = 0.f;
        for (int j = 0; j < 64; ++j)
            s += mb2[l * 64 + j] * uw1[l * 8192 + (64 + j) * 64 + hid];
        cvec[gid] = s;
    }
    if (gid < 128 * 64) {
        int j = gid >> 6, k = gid & 63;
        float w = ow[k * 128 + j];
        bf16_t hi = (bf16_t)w;
        whi[gid] = hi;
        wlo[gid] = (bf16_t)(w - (float)hi);
    }
}

// ---------------- counting sort of edges by destination ----------------
__global__ void k_hist(const int* __restrict__ ei, int* __restrict__ deg) {
    int gid = blockIdx.x * blockDim.x + threadIdx.x;
    if (gid < NE) atomicAdd(&deg[ei[NE + gid]], 1);
}

#define SCAN_BLKS 196
__global__ void k_scan1(const int* __restrict__ deg, int* __restrict__ tscan,
                        int* __restrict__ part) {
    __shared__ int lds[256];
    int tid = threadIdx.x;
    int gid = blockIdx.x * 256 + tid;
    int v = (gid < NN) ? deg[gid] : 0;
    lds[tid] = v;
    __syncthreads();
    for (int off = 1; off < 256; off <<= 1) {
        int t = (tid >= off) ? lds[tid - off] : 0;
        __syncthreads();
        lds[tid] += t;
        __syncthreads();
    }
    if (gid < NN) tscan[gid] = lds[tid] - v;
    if (tid == 255) part[blockIdx.x] = lds[255];
}

// fused scan2+scan3: every block redundantly scans the 196 partials in LDS,
// picks its own exclusive prefix, then finalizes offs/cursor for its chunk.
__global__ void k_scan23(const int* __restrict__ tscan, const int* __restrict__ part,
                         int* __restrict__ offs, int* __restrict__ cursor) {
    __shared__ int lds[256];
    int tid = threadIdx.x;
    int v = (tid < SCAN_BLKS) ? part[tid] : 0;
    lds[tid] = v;
    __syncthreads();
    for (int off = 1; off < 256; off <<= 1) {
        int t = (tid >= off) ? lds[tid - off] : 0;
        __syncthreads();
        lds[tid] += t;
        __syncthreads();
    }
    // exclusive prefix for this block
    __shared__ int base;
    if (tid == 0) base = (blockIdx.x > 0) ? lds[blockIdx.x - 1] : 0;
    __syncthreads();
    int gid = blockIdx.x * 256 + tid;
    if (gid < NN) {
        int o = tscan[gid] + base;
        offs[gid] = o;
        cursor[gid] = o;
    }
    if (gid == 0) offs[NN] = NE;
}

__global__ void k_scatter(const int* __restrict__ ei, int* __restrict__ cursor,
                          u16* __restrict__ ssrc) {
    int gid = blockIdx.x * blockDim.x + threadIdx.x;
    if (gid < NE) {
        int c = ei[NE + gid];
        int pos = atomicAdd(&cursor[c], 1);
        ssrc[pos] = (u16)ei[gid];
    }
}

// ---------------- fused input projection + layer-0 P/Q ----------------
__global__ __launch_bounds__(256)
void k_inputpq(const float* __restrict__ x, const float* __restrict__ iw,
               const float* __restrict__ ib,
               const bf16_t* __restrict__ w1t, const float* __restrict__ b1,
               bf16_t* __restrict__ h, bf16_t* __restrict__ P, bf16_t* __restrict__ Q) {
    const int lane = threadIdx.x & 63;
    const int g = lane >> 4;
    const int m16 = lane & 15;
    const int wid = (blockIdx.x * blockDim.x + threadIdx.x) >> 6;
    const int nw = (gridDim.x * blockDim.x) >> 6;

    bf16x8 wtop[2][4], wbot[2][4];
    #pragma unroll
    for (int s = 0; s < 2; ++s)
        #pragma unroll
        for (int nt = 0; nt < 4; ++nt) {
            wtop[s][nt] = load_frag(w1t + (16 * nt + m16) * 128 + 32 * s + 4 * g);
            wbot[s][nt] = load_frag(w1t + (16 * nt + m16) * 128 + 64 + 32 * s + 4 * g);
        }
    float b1f[4][4];
    #pragma unroll
    for (int nt = 0; nt < 4; ++nt)
        #pragma unroll
        for (int r = 0; r < 4; ++r) b1f[nt][r] = b1[16 * nt + 4 * g + r];

    float wcol[3][2][8], bcol[2][8];
    #pragma unroll
    for (int s = 0; s < 2; ++s)
        #pragma unroll
        for (int j = 0; j < 8; ++j) {
            int f = 32 * s + 4 * g + (j < 4 ? j : 16 + j - 4);
            bcol[s][j] = ib[f];
            #pragma unroll
            for (int i = 0; i < 3; ++i) wcol[i][s][j] = iw[i * 64 + f];
        }

    const int ntiles = NN / 16;
    for (int t = wid; t < ntiles; t += nw) {
        const int node = t * 16 + m16;
        float x0 = x[node * 3 + 0], x1 = x[node * 3 + 1], x2 = x[node * 3 + 2];
        bf16x8 hb[2];
        #pragma unroll
        for (int s = 0; s < 2; ++s)
            #pragma unroll
            for (int j = 0; j < 8; ++j) {
                float hf = bcol[s][j] + x0 * wcol[0][s][j] + x1 * wcol[1][s][j]
                         + x2 * wcol[2][s][j];
                hb[s][j] = (bf16_t)hf;
            }
        #pragma unroll
        for (int s = 0; s < 2; ++s) {
            bf16x4 lo, hi;
            #pragma unroll
            for (int j = 0; j < 4; ++j) { lo[j] = hb[s][j]; hi[j] = hb[s][4 + j]; }
            *(bf16x4*)(h + node * 64 + 32 * s + 4 * g) = lo;
            *(bf16x4*)(h + node * 64 + 32 * s + 16 + 4 * g) = hi;
        }

        f32x4 accP[4], accQ[4];
        #pragma unroll
        for (int nt = 0; nt < 4; ++nt) {
            accP[nt] = (f32x4){0.f, 0.f, 0.f, 0.f};
            accQ[nt] = (f32x4){0.f, 0.f, 0.f, 0.f};
        }
        #pragma unroll
        for (int s = 0; s < 2; ++s)
            #pragma unroll
            for (int nt = 0; nt < 4; ++nt) {
                accP[nt] = __builtin_amdgcn_mfma_f32_16x16x32_bf16(wtop[s][nt], hb[s], accP[nt], 0, 0, 0);
                accQ[nt] = __builtin_amdgcn_mfma_f32_16x16x32_bf16(wbot[s][nt], hb[s], accQ[nt], 0, 0, 0);
            }
        #pragma unroll
        for (int nt = 0; nt < 4; ++nt) {
            bf16x4 vp, vq;
            #pragma unroll
            for (int r = 0; r < 4; ++r) {
                vp[r] = (bf16_t)accP[nt][r];
                vq[r] = (bf16_t)(accQ[nt][r] + b1f[nt][r]);
            }
            *(bf16x4*)(P + node * 64 + 16 * nt + 4 * g) = vp;
            *(bf16x4*)(Q + node * 64 + 16 * nt + 4 * g) = vq;
        }
    }
}

// ---------------- per-layer edge phase, split-2, u16 sources ----------------
__global__ void k_edge(const bf16_t* __restrict__ P, const bf16_t* __restrict__ Q,
                       const u16* __restrict__ ssrc, const int* __restrict__ offs,
                       bf16_t* __restrict__ S, bf16_t* __restrict__ S2) {
    int gid = blockIdx.x * blockDim.x + threadIdx.x;
    int oct = gid >> 3, f8 = gid & 7;
    int node = oct >> 1, half = oct & 1;
    if (node >= NN) return;
    bf16x8 qv = *(const bf16x8*)(Q + node * 64 + f8 * 8);
    float qf[8], a[8];
    #pragma unroll
    for (int r = 0; r < 8; ++r) { qf[r] = (float)qv[r]; a[r] = 0.f; }
    const int b0 = offs[node], e0 = offs[node + 1];
    const int mid = b0 + ((e0 - b0 + 1) >> 1);
    const int beg = half ? mid : b0;
    const int end = half ? e0 : mid;
    int p = beg;
    const int n4 = beg + ((end - beg) & ~3);
    for (; p < n4; p += 4) {
        int s0 = ssrc[p], s1 = ssrc[p + 1], s2 = ssrc[p + 2], s3 = ssrc[p + 3];
        bf16x8 v0 = *(const bf16x8*)(P + s0 * 64 + f8 * 8);
        bf16x8 v1 = *(const bf16x8*)(P + s1 * 64 + f8 * 8);
        bf16x8 v2 = *(const bf16x8*)(P + s2 * 64 + f8 * 8);
        bf16x8 v3 = *(const bf16x8*)(P + s3 * 64 + f8 * 8);
        #pragma unroll
        for (int r = 0; r < 8; ++r) {
            float x0 = (float)v0[r] + qf[r];
            float x1 = (float)v1[r] + qf[r];
            float x2 = (float)v2[r] + qf[r];
            float x3 = (float)v3[r] + qf[r];
            a[r] += (x0 > 0.f ? x0 : 0.f) + (x1 > 0.f ? x1 : 0.f)
                  + (x2 > 0.f ? x2 : 0.f) + (x3 > 0.f ? x3 : 0.f);
        }
    }
    for (; p < end; ++p) {
        int s = ssrc[p];
        bf16x8 v = *(const bf16x8*)(P + s * 64 + f8 * 8);
        #pragma unroll
        for (int r = 0; r < 8; ++r) {
            float x = (float)v[r] + qf[r];
            a[r] += x > 0.f ? x : 0.f;
        }
    }
    bf16x8 sv;
    #pragma unroll
    for (int r = 0; r < 8; ++r) sv[r] = (bf16_t)a[r];
    bf16_t* dst = half ? S2 : S;
    *(bf16x8*)(dst + node * 64 + f8 * 8) = sv;
}

// ---------------- fused update + next-layer P/Q ----------------
__global__ __launch_bounds__(256)
void k_updpq(const bf16_t* __restrict__ h, const bf16_t* __restrict__ S,
             const bf16_t* __restrict__ S2, const int* __restrict__ deg,
             const bf16_t* __restrict__ u1t, const bf16_t* __restrict__ w2u,
             const bf16_t* __restrict__ u2t,
             const float* __restrict__ ub1, const float* __restrict__ cvec,
             const float* __restrict__ ub2,
             const bf16_t* __restrict__ w1tn, const float* __restrict__ b1n,
             bf16_t* __restrict__ hn, bf16_t* __restrict__ P, bf16_t* __restrict__ Q) {
    const int lane = threadIdx.x & 63;
    const int g = lane >> 4;
    const int m16 = lane & 15;
    const int wid = (blockIdx.x * blockDim.x + threadIdx.x) >> 6;
    const int nw = (gridDim.x * blockDim.x) >> 6;

    bf16x8 u1f[2][4], w2f[2][4], u2f[2][4], wtop[2][4], wbot[2][4];
    #pragma unroll
    for (int s = 0; s < 2; ++s)
        #pragma unroll
        for (int nt = 0; nt < 4; ++nt) {
            u1f[s][nt] = load_frag(u1t + (16 * nt + m16) * 64 + 32 * s + 4 * g);
            w2f[s][nt] = load_frag(w2u + (16 * nt + m16) * 64 + 32 * s + 4 * g);
            u2f[s][nt] = load_frag(u2t + (16 * nt + m16) * 64 + 32 * s + 4 * g);
            wtop[s][nt] = load_frag(w1tn + (16 * nt + m16) * 128 + 32 * s + 4 * g);
            wbot[s][nt] = load_frag(w1tn + (16 * nt + m16) * 128 + 64 + 32 * s + 4 * g);
        }
    float b1f[4][4], cf[4][4], b2f[4][4], b1nf[4][4];
    #pragma unroll
    for (int nt = 0; nt < 4; ++nt)
        #pragma unroll
        for (int r = 0; r < 4; ++r) {
            b1f[nt][r] = ub1[16 * nt + 4 * g + r];
            cf[nt][r] = cvec[16 * nt + 4 * g + r];
            b2f[nt][r] = ub2[16 * nt + 4 * g + r];
            b1nf[nt][r] = b1n[16 * nt + 4 * g + r];
        }

    const int ntiles = NN / 16;
    for (int t = wid; t < ntiles; t += nw) {
        const int node = t * 16 + m16;
        bf16x8 hfr[2], sfr[2];
        hfr[0] = load_frag(h + node * 64 + 4 * g);
        hfr[1] = load_frag(h + node * 64 + 4 * g + 32);
        sfr[0] = load_frag2(S + node * 64 + 4 * g, S2 + node * 64 + 4 * g);
        sfr[1] = load_frag2(S + node * 64 + 4 * g + 32, S2 + node * 64 + 4 * g + 32);
        float dv = (float)deg[node];

        f32x4 acc1[4];
        #pragma unroll
        for (int nt = 0; nt < 4; ++nt) acc1[nt] = (f32x4){0.f, 0.f, 0.f, 0.f};
        #pragma unroll
        for (int s = 0; s < 2; ++s)
            #pragma unroll
            for (int nt = 0; nt < 4; ++nt) {
                acc1[nt] = __builtin_amdgcn_mfma_f32_16x16x32_bf16(u1f[s][nt], hfr[s], acc1[nt], 0, 0, 0);
                acc1[nt] = __builtin_amdgcn_mfma_f32_16x16x32_bf16(w2f[s][nt], sfr[s], acc1[nt], 0, 0, 0);
            }

        bf16x8 hb[2];
        #pragma unroll
        for (int s = 0; s < 2; ++s) {
            bf16x8 f;
            #pragma unroll
            for (int half = 0; half < 2; ++half) {
                const int nt = 2 * s + half;
                #pragma unroll
                for (int r = 0; r < 4; ++r) {
                    float v = acc1[nt][r] + b1f[nt][r] + dv * cf[nt][r];
                    v = v > 0.f ? v : 0.f;
                    f[4 * half + r] = (bf16_t)v;
                }
            }
            hb[s] = f;
        }

        f32x4 acc2[4];
        #pragma unroll
        for (int nt = 0; nt < 4; ++nt) acc2[nt] = (f32x4){0.f, 0.f, 0.f, 0.f};
        #pragma unroll
        for (int s = 0; s < 2; ++s)
            #pragma unroll
            for (int nt = 0; nt < 4; ++nt)
                acc2[nt] = __builtin_amdgcn_mfma_f32_16x16x32_bf16(u2f[s][nt], hb[s], acc2[nt], 0, 0, 0);

        bf16x8 hb2[2];
        #pragma unroll
        for (int s = 0; s < 2; ++s) {
            bf16x8 f;
            #pragma unroll
            for (int half = 0; half < 2; ++half) {
                const int nt = 2 * s + half;
                #pragma unroll
                for (int r = 0; r < 4; ++r) {
                    float v = acc2[nt][r] + b2f[nt][r];
                    f[4 * half + r] = (bf16_t)(v > 0.f ? v : 0.f);
                }
            }
            hb2[s] = f;
        }
        #pragma unroll
        for (int s = 0; s < 2; ++s) {
            bf16x4 lo, hi;
            #pragma unroll
            for (int j = 0; j < 4; ++j) { lo[j] = hb2[s][j]; hi[j] = hb2[s][4 + j]; }
            *(bf16x4*)(hn + node * 64 + 32 * s + 4 * g) = lo;
            *(bf16x4*)(hn + node * 64 + 32 * s + 16 + 4 * g) = hi;
        }

        f32x4 accP[4], accQ[4];
        #pragma unroll
        for (int nt = 0; nt < 4; ++nt) {
            accP[nt] = (f32x4){0.f, 0.f, 0.f, 0.f};
            accQ[nt] = (f32x4){0.f, 0.f, 0.f, 0.f};
        }
        #pragma unroll
        for (int s = 0; s < 2; ++s)
            #pragma unroll
            for (int nt = 0; nt < 4; ++nt) {
                accP[nt] = __builtin_amdgcn_mfma_f32_16x16x32_bf16(wtop[s][nt], hb2[s], accP[nt], 0, 0, 0);
                accQ[nt] = __builtin_amdgcn_mfma_f32_16x16x32_bf16(wbot[s][nt], hb2[s], accQ[nt], 0, 0, 0);
            }
        #pragma unroll
        for (int nt = 0; nt < 4; ++nt) {
            bf16x4 vp, vq;
            #pragma unroll
            for (int r = 0; r < 4; ++r) {
                vp[r] = (bf16_t)accP[nt][r];
                vq[r] = (bf16_t)(accQ[nt][r] + b1nf[nt][r]);
            }
            *(bf16x4*)(P + node * 64 + 16 * nt + 4 * g) = vp;
            *(bf16x4*)(Q + node * 64 + 16 * nt + 4 * g) = vq;
        }
    }
}

// ---------------- plain update (last layer) ----------------
__global__ void k_upd(const bf16_t* __restrict__ h, const bf16_t* __restrict__ S,
                      const bf16_t* __restrict__ S2, const int* __restrict__ deg,
                      const bf16_t* __restrict__ u1t, const bf16_t* __restrict__ w2u,
                      const bf16_t* __restrict__ u2t,
                      const float* __restrict__ ub1, const float* __restrict__ cvec,
                      const float* __restrict__ ub2, bf16_t* __restrict__ hn) {
    const int lane = threadIdx.x & 63;
    const int g = lane >> 4;
    const int m16 = lane & 15;
    const int wid = (blockIdx.x * blockDim.x + threadIdx.x) >> 6;
    const int nw = (gridDim.x * blockDim.x) >> 6;

    bf16x8 u1f[2][4], w2f[2][4], u2f[2][4];
    #pragma unroll
    for (int s = 0; s < 2; ++s)
        #pragma unroll
        for (int nt = 0; nt < 4; ++nt) {
            u1f[s][nt] = load_frag(u1t + (16 * nt + m16) * 64 + 32 * s + 4 * g);
            w2f[s][nt] = load_frag(w2u + (16 * nt + m16) * 64 + 32 * s + 4 * g);
            u2f[s][nt] = load_frag(u2t + (16 * nt + m16) * 64 + 32 * s + 4 * g);
        }
    float b1f[4][4], cf[4][4], b2f[4][4];
    #pragma unroll
    for (int nt = 0; nt < 4; ++nt)
        #pragma unroll
        for (int r = 0; r < 4; ++r) {
            b1f[nt][r] = ub1[16 * nt + 4 * g + r];
            cf[nt][r] = cvec[16 * nt + 4 * g + r];
            b2f[nt][r] = ub2[16 * nt + 4 * g + r];
        }

    const int ntiles = NN / 16;
    for (int t = wid; t < ntiles; t += nw) {
        const int node = t * 16 + m16;
        bf16x8 hfr[2], sfr[2];
        hfr[0] = load_frag(h + node * 64 + 4 * g);
        hfr[1] = load_frag(h + node * 64 + 4 * g + 32);
        sfr[0] = load_frag2(S + node * 64 + 4 * g, S2 + node * 64 + 4 * g);
        sfr[1] = load_frag2(S + node * 64 + 4 * g + 32, S2 + node * 64 + 4 * g + 32);
        float dv = (float)deg[node];

        f32x4 acc1[4];
        #pragma unroll
        for (int nt = 0; nt < 4; ++nt) acc1[nt] = (f32x4){0.f, 0.f, 0.f, 0.f};
        #pragma unroll
        for (int s = 0; s < 2; ++s)
            #pragma unroll
            for (int nt = 0; nt < 4; ++nt) {
                acc1[nt] = __builtin_amdgcn_mfma_f32_16x16x32_bf16(u1f[s][nt], hfr[s], acc1[nt], 0, 0, 0);
                acc1[nt] = __builtin_amdgcn_mfma_f32_16x16x32_bf16(w2f[s][nt], sfr[s], acc1[nt], 0, 0, 0);
            }

        bf16x8 hb[2];
        #pragma unroll
        for (int s = 0; s < 2; ++s) {
            bf16x8 f;
            #pragma unroll
            for (int half = 0; half < 2; ++half) {
                const int nt = 2 * s + half;
                #pragma unroll
                for (int r = 0; r < 4; ++r) {
                    float v = acc1[nt][r] + b1f[nt][r] + dv * cf[nt][r];
                    v = v > 0.f ? v : 0.f;
                    f[4 * half + r] = (bf16_t)v;
                }
            }
            hb[s] = f;
        }

        f32x4 acc2[4];
        #pragma unroll
        for (int nt = 0; nt < 4; ++nt) acc2[nt] = (f32x4){0.f, 0.f, 0.f, 0.f};
        #pragma unroll
        for (int s = 0; s < 2; ++s)
            #pragma unroll
            for (int nt = 0; nt < 4; ++nt)
                acc2[nt] = __builtin_amdgcn_mfma_f32_16x16x32_bf16(u2f[s][nt], hb[s], acc2[nt], 0, 0, 0);

        #pragma unroll
        for (int nt = 0; nt < 4; ++nt) {
            bf16x4 v4;
            #pragma unroll
            for (int r = 0; r < 4; ++r) {
                float v = acc2[nt][r] + b2f[nt][r];
                v4[r] = (bf16_t)(v > 0.f ? v : 0.f);
            }
            *(bf16x4*)(hn + node * 64 + 16 * nt + 4 * g) = v4;
        }
    }
}

// ---------------- output projection (MFMA, split hi/lo weights) ----------------
__global__ __launch_bounds__(256)
void k_outm(const bf16_t* __restrict__ whi_t, const bf16_t* __restrict__ wlo_t,
            const bf16_t* __restrict__ h, const float* __restrict__ b,
            float* __restrict__ out) {
    const int lane = threadIdx.x & 63;
    const int g = lane >> 4;
    const int m16 = lane & 15;
    const int wid = (blockIdx.x * blockDim.x + threadIdx.x) >> 6;
    const int nw = (gridDim.x * blockDim.x) >> 6;

    bf16x8 whi[2][8], wlo[2][8];
    #pragma unroll
    for (int s = 0; s < 2; ++s)
        #pragma unroll
        for (int nt = 0; nt < 8; ++nt) {
            whi[s][nt] = load_frag(whi_t + (16 * nt + m16) * 64 + 32 * s + 4 * g);
            wlo[s][nt] = load_frag(wlo_t + (16 * nt + m16) * 64 + 32 * s + 4 * g);
        }
    f32x4 bfv[8];
    #pragma unroll
    for (int nt = 0; nt < 8; ++nt)
        #pragma unroll
        for (int r = 0; r < 4; ++r) bfv[nt][r] = b[16 * nt + 4 * g + r];

    const int ntiles = NN / 16;
    for (int t = wid; t < ntiles; t += nw) {
        const int node = t * 16 + m16;
        bf16x8 hfr[2];
        hfr[0] = load_frag(h + node * 64 + 4 * g);
        hfr[1] = load_frag(h + node * 64 + 4 * g + 32);

        f32x4 acc[8];
        #pragma unroll
        for (int nt = 0; nt < 8; ++nt) acc[nt] = (f32x4){0.f, 0.f, 0.f, 0.f};
        #pragma unroll
        for (int s = 0; s < 2; ++s)
            #pragma unroll
            for (int nt = 0; nt < 8; ++nt) {
                acc[nt] = __builtin_amdgcn_mfma_f32_16x16x32_bf16(whi[s][nt], hfr[s], acc[nt], 0, 0, 0);
                acc[nt] = __builtin_amdgcn_mfma_f32_16x16x32_bf16(wlo[s][nt], hfr[s], acc[nt], 0, 0, 0);
            }
        #pragma unroll
        for (int nt = 0; nt < 8; ++nt)
            *(f32x4*)(out + node * 128 + 16 * nt + 4 * g) = acc[nt] + bfv[nt];
    }
}

extern "C" void kernel_launch(void* const* d_in, const int* in_sizes, int n_in,
                              void* d_out, int out_size, void* d_ws, size_t ws_size,
                              hipStream_t stream) {
    const float* x      = (const float*)d_in[0];
    const int*   ei     = (const int*)d_in[1];
    const float* in_w   = (const float*)d_in[2];
    const float* in_b   = (const float*)d_in[3];
    const float* msg_w1 = (const float*)d_in[4];
    const float* msg_b1 = (const float*)d_in[5];
    const float* msg_w2 = (const float*)d_in[6];
    const float* msg_b2 = (const float*)d_in[7];
    const float* upd_w1 = (const float*)d_in[8];
    const float* upd_b1 = (const float*)d_in[9];
    const float* upd_w2 = (const float*)d_in[10];
    const float* upd_b2 = (const float*)d_in[11];
    const float* out_w  = (const float*)d_in[12];
    const float* out_b  = (const float*)d_in[13];
    float* out = (float*)d_out;

    char* ws = (char*)d_ws;
    bf16_t* h_a    = (bf16_t*)(ws);
    bf16_t* h_b    = (bf16_t*)(ws + 6400000);
    bf16_t* P      = (bf16_t*)(ws + 12800000);
    bf16_t* Q      = (bf16_t*)(ws + 19200000);
    bf16_t* S      = (bf16_t*)(ws + 25600000);
    u16*    ssrc   = (u16*)   (ws + 32000000);   // 1.6 MB (u16)
    int*    deg    = (int*)   (ws + 35200000);
    int*    offs   = (int*)   (ws + 35400000);
    int*    cursor = (int*)   (ws + 35600128);
    int*    tscan  = (int*)   (ws + 35800192);
    int*    part   = (int*)   (ws + 36000256);
    bf16_t* w1t    = (bf16_t*)(ws + 36002304);
    bf16_t* u1t    = (bf16_t*)(ws + 36051456);
    bf16_t* u2t    = (bf16_t*)(ws + 36076032);
    bf16_t* w2u    = (bf16_t*)(ws + 36100608);
    float*  cvec   = (float*) (ws + 36125184);
    bf16_t* whi    = (bf16_t*)(ws + 36126208);   // 16 KB
    bf16_t* wlo    = (bf16_t*)(ws + 36142592);   // 16 KB
    bf16_t* S2     = (bf16_t*)(ws + 36160000);   // 6.4 MB

    // fused weight prep + deg zeroing
    k_prepall<<<96, 256, 0, stream>>>(msg_w1, upd_w1, upd_w2, msg_w2, msg_b2, out_w,
                                      w1t, u1t, u2t, w2u, cvec, whi, wlo, deg);

    // counting sort of edges by destination
    k_hist<<<(NE + 255) / 256, 256, 0, stream>>>(ei, deg);
    k_scan1<<<SCAN_BLKS, 256, 0, stream>>>(deg, tscan, part);
    k_scan23<<<SCAN_BLKS, 256, 0, stream>>>(tscan, part, offs, cursor);
    k_scatter<<<(NE + 255) / 256, 256, 0, stream>>>(ei, cursor, ssrc);

    // fused input projection + layer-0 P/Q
    k_inputpq<<<512, 256, 0, stream>>>(x, in_w, in_b, w1t, msg_b1, h_a, P, Q);

    bf16_t* hc = h_a;
    bf16_t* hn = h_b;
    for (int l = 0; l < 3; ++l) {
        k_edge<<<(NN * 16 + 255) / 256, 256, 0, stream>>>(P, Q, ssrc, offs, S, S2);
        if (l < 2) {
            k_updpq<<<512, 256, 0, stream>>>(hc, S, S2, deg,
                u1t + l * 4096, w2u + l * 4096, u2t + l * 4096,
                upd_b1 + l * 64, cvec + l * 64, upd_b2 + l * 64,
                w1t + (l + 1) * 8192, msg_b1 + (l + 1) * 64,
                hn, P, Q);
        } else {
            k_upd<<<512, 256, 0, stream>>>(hc, S, S2, deg,
                u1t + l * 4096, w2u + l * 4096, u2t + l * 4096,
                upd_b1 + l * 64, cvec + l * 64, upd_b2 + l * 64, hn);
        }
        bf16_t* tmp = hc; hc = hn; hn = tmp;
    }
    k_outm<<<640, 256, 0, stream>>>(whi, wlo, hc, out_b, out);
}